// Round 7
// baseline (215.159 us; speedup 1.0000x reference)
//
#include <hip/hip_runtime.h>
#include <hip/hip_bf16.h>

// ---------------- problem constants ----------------
#define BATCH   4
#define SEQ     2048
#define DMODEL  512
#define NHEADS  8
#define HEADDIM 64
#define MTOT    (BATCH*SEQ)      // 8192 rows
#define NX      (MTOT*DMODEL)    // 4194304 x elements
#define NW      (DMODEL*DMODEL)  // 262144 weight elements
#define QTILE   128
#define KTILE   64
#define NKT     (SEQ/KTILE)      // 32

#define LOG2E   1.4426950408889634f
#define SCL2    0.18033688011112042f      // 0.125 * log2e
#define SHIFT   14.426950408889634f       // 10 * log2e (overflow headroom shift)
// ---------------------------------------------------

typedef unsigned short u16;
typedef __bf16 bf16x8 __attribute__((ext_vector_type(8)));
typedef float  f32x4  __attribute__((ext_vector_type(4)));
typedef unsigned short u16x4 __attribute__((ext_vector_type(4)));
typedef unsigned u32x2 __attribute__((ext_vector_type(2)));

#define MFMA(a,b,c) __builtin_amdgcn_mfma_f32_16x16x32_bf16(a,b,c,0,0,0)

__device__ __forceinline__ u16 f2bf(float f) {
    unsigned u = __float_as_uint(f);
    u += 0x7FFFu + ((u >> 16) & 1u);   // round-to-nearest-even
    return (u16)(u >> 16);
}

// two f32 -> packed bf16 pair (low = a), RNE
__device__ __forceinline__ unsigned pk_bf16(float a, float b) {
    union { __hip_bfloat162 h; unsigned u; } cv;
    cv.h = __float22bfloat162_rn(make_float2(a, b));
    return cv.u;
}

__device__ __forceinline__ float qsum16(float v) {
    v += __shfl_xor(v, 1);
    v += __shfl_xor(v, 2);
    v += __shfl_xor(v, 4);
    v += __shfl_xor(v, 8);
    return v;
}

// async global->LDS (wave-uniform LDS base + lane*size)
__device__ __forceinline__ void gll16(const void* g, void* l) {
    __builtin_amdgcn_global_load_lds((const __attribute__((address_space(1))) void*)g,
                                     (__attribute__((address_space(3))) void*)l, 16, 0, 0);
}
__device__ __forceinline__ void gll4(const void* g, void* l) {
    __builtin_amdgcn_global_load_lds((const __attribute__((address_space(1))) void*)g,
                                     (__attribute__((address_space(3))) void*)l, 4, 0, 0);
}

// ---------------- kernel 0: fp32 -> bf16 converts + rope cos/sin table ----------------
#define NCVT4 ((NX + 4*NW)/4)    // 1310720 float4 groups
__global__ __launch_bounds__(256) void cvt_rope_kernel(
    const float* __restrict__ x,
    const float* __restrict__ wq, const float* __restrict__ wk,
    const float* __restrict__ wv, const float* __restrict__ wo,
    u16* __restrict__ xbf,
    u16* __restrict__ wqbf, u16* __restrict__ wkbf,
    u16* __restrict__ wvbf, u16* __restrict__ wobf,
    float2* __restrict__ cst)
{
    int i4 = blockIdx.x * 256 + threadIdx.x;
    if (i4 < NCVT4) {
        int i = i4 * 4;
        const float* s; u16* d; int o;
        if (i < NX) { s = x; d = xbf; o = i; }
        else {
            int j = i - NX;
            int r = j >> 18;            // NW = 2^18
            o = j & (NW - 1);
            s = (r == 0) ? wq : (r == 1) ? wk : (r == 2) ? wv : wo;
            d = (r == 0) ? wqbf : (r == 1) ? wkbf : (r == 2) ? wvbf : wobf;
        }
        float4 v = *(const float4*)(s + o);
        u16x4 u = { f2bf(v.x), f2bf(v.y), f2bf(v.z), f2bf(v.w) };
        *(u16x4*)(d + o) = u;
    } else {
        int r = i4 - NCVT4;             // [0, 16384)
        if (r < SEQ * 32 / 4) {
            int idx = r * 4;
            int s  = idx >> 5;
            int p0 = idx & 31;
#pragma unroll
            for (int t = 0; t < 4; ++t) {
                int p = p0 + t;
                float inv = __expf(-0.5756462732485115f * (float)(p & 15));
                float ang = (float)s * inv;
                cst[idx + t] = make_float2(cosf(ang), sinf(ang));
            }
        }
    }
}

// ---------------- kernel 1: fused QKV projection + RoPE (128x128, LDS-staged) ----------------
// Q: rope, linear (bh, s, d).   K: rope, linear (bh, s, d).
// V: transposed linear (bh, d, s) via LDS-transpose + coalesced 256B-run stores.
#define TP 136   // transpose tile row stride (u16 elems)
__global__ __launch_bounds__(256) void qkv_kernel(
    const u16* __restrict__ x,
    const u16* __restrict__ Wq, const float* __restrict__ bq,
    const u16* __restrict__ Wk, const float* __restrict__ bk,
    const u16* __restrict__ Wv, const float* __restrict__ bv,
    const float2* __restrict__ cst,
    u16* __restrict__ qws, u16* __restrict__ kws, u16* __restrict__ vtws)
{
    __shared__ alignas(16) u16 smem[128 * TP];   // 34816 B; As/Bs alias the front
    u16* As = smem;            // 128*64 = 8192 elems
    u16* Bs = smem + 8192;

    const int m0 = blockIdx.x * 128;         // row tile (64 tiles)
    const int n0 = blockIdx.y * 128;         // col tile over 1536 (12 tiles)
    const int tid  = threadIdx.x;
    const int w    = tid >> 6;
    const int lane = tid & 63;
    const int quad = lane >> 4;
    const int l16  = lane & 15;
    const int wm = w & 1, wn = w >> 1;       // 2x2 wave grid, each wave 64x64

    const int sec = n0 >> 9;                 // 0=Q 1=K 2=V
    const int oc0 = n0 & 511;
    const u16*   Wm = (sec == 0) ? Wq : (sec == 1 ? Wk : Wv);
    const float* bb = (sec == 0) ? bq : (sec == 1 ? bk : bv);
    const float  sgn = (l16 & 1) ? 1.0f : -1.0f;   // rope sign, lane-parity const

    f32x4 acc[4][4] = {};

    for (int kb = 0; kb < 8; ++kb) {
        // ---- stage A,B tiles: slot s covers LDS bytes [s*16, s*16+16) ----
#pragma unroll
        for (int it = 0; it < 4; ++it) {
            const int s   = it * 256 + tid;
            const int row = s >> 3;
            const int cb  = s & 7;
            const int gcol = kb * 64 + (((cb ^ (row & 7))) << 3);
            gll16(x  + (m0  + row) * 512 + gcol, &As[s * 8]);
            gll16(Wm + (oc0 + row) * 512 + gcol, &Bs[s * 8]);
        }
        __syncthreads();

#pragma unroll
        for (int ks = 0; ks < 2; ++ks) {
            bf16x8 a[4], bfr[4];
#pragma unroll
            for (int t = 0; t < 4; ++t) {
                const int arow = wm * 64 + t * 16 + l16;
                a[t]   = *(const bf16x8*)&As[arow * 64 + (((ks * 4 + quad) ^ (arow & 7)) << 3)];
                const int brow = wn * 64 + t * 16 + l16;
                bfr[t] = *(const bf16x8*)&Bs[brow * 64 + (((ks * 4 + quad) ^ (brow & 7)) << 3)];
            }
#pragma unroll
            for (int tm = 0; tm < 4; ++tm)
#pragma unroll
                for (int tn = 0; tn < 4; ++tn)
                    acc[tm][tn] = MFMA(a[tm], bfr[tn], acc[tm][tn]);
        }
        __syncthreads();
    }

    if (sec < 2) {
        // ---- Q/K epilogue: bias + rope, linear (s,d) store ----
#pragma unroll
        for (int tm = 0; tm < 4; ++tm) {
            const int R0 = m0 + wm * 64 + tm * 16 + quad * 4;   // rows R0..R0+3
            const int bi = R0 >> 11;
            const int s0 = R0 & 2047;
#pragma unroll
            for (int tn = 0; tn < 4; ++tn) {
                const int col = oc0 + wn * 64 + tn * 16 + l16;   // [0,512)
                const int hh  = col >> 6;
                const int d   = col & 63;
                const float bval = bb[col];
                const size_t hb = (size_t)(bi * NHEADS + hh) * (SEQ * HEADDIM);
                float res[4];
#pragma unroll
                for (int r = 0; r < 4; ++r) {
                    float val = acc[tm][tn][r] + bval;
                    float other = __shfl_xor(val, 1);
                    float2 cs = cst[(s0 + r) * 32 + (d >> 1)];
                    res[r] = fmaf(val, cs.x, other * (sgn * cs.y));
                }
                const unsigned p01 = pk_bf16(res[0], res[1]);
                const unsigned p23 = pk_bf16(res[2], res[3]);
                u16* dp = ((sec == 0) ? qws : kws) + hb + (size_t)s0 * HEADDIM + d;
                dp[0]   = (u16)p01;  dp[64]  = (u16)(p01 >> 16);
                dp[128] = (u16)p23;  dp[192] = (u16)(p23 >> 16);
            }
        }
    } else {
        // ---- V epilogue: bias, LDS transpose tile T[col][row], coalesced V^T store ----
        // (main loop ended with __syncthreads, As/Bs dead -> reuse smem as T)
#pragma unroll
        for (int tm = 0; tm < 4; ++tm) {
            const int row_l = wm * 64 + tm * 16 + quad * 4;      // local s rows
#pragma unroll
            for (int tn = 0; tn < 4; ++tn) {
                const int col_l = wn * 64 + tn * 16 + l16;       // local out-col
                const float bval = bb[oc0 + col_l];
                u32x2 pv = { pk_bf16(acc[tm][tn][0] + bval, acc[tm][tn][1] + bval),
                             pk_bf16(acc[tm][tn][2] + bval, acc[tm][tn][3] + bval) };
                *(u32x2*)&smem[col_l * TP + row_l] = pv;
            }
        }
        __syncthreads();
        const int bi  = m0 >> 11;
        const int sgb = m0 & 2047;
#pragma unroll
        for (int i = 0; i < 8; ++i) {
            const int c    = i * 256 + tid;      // [0, 2048)
            const int col  = c >> 4;             // local out-col
            const int sc8  = (c & 15) * 8;       // s-chunk (8 elems = 16B)
            const int gcol = oc0 + col;
            const int hh   = gcol >> 6;
            const int d    = gcol & 63;
            u16* dst = vtws + (size_t)(bi * NHEADS + hh) * (SEQ * HEADDIM)
                            + (size_t)d * SEQ + sgb + sc8;
            *(bf16x8*)dst = *(const bf16x8*)&smem[col * TP + sc8];
        }
    }
}

// ---------------- kernel 2: flash attention, 4 waves x 2 m-subtiles ----------------
// grid: (SEQ/QTILE, B*H) = (16, 32). block 256 = 4 waves; wave owns 32 q rows
// (subtiles at q0 + s*64 + w*16). K/V frags loaded once per nt, reused by both subtiles.
__global__ __launch_bounds__(256) void attn_kernel(
    const u16* __restrict__ qws, const u16* __restrict__ kws,
    const u16* __restrict__ vtl,
    const int* __restrict__ vids, const float* __restrict__ mask,
    const float* __restrict__ u_same, const float* __restrict__ u_cross,
    u16* __restrict__ attn)
{
    __shared__ alignas(16) u16 kbuf[2][KTILE * 64];   // 8 KB each, swizzled tiles
    __shared__ alignas(16) u16 vbuf[2][KTILE * 64];
    __shared__ alignas(16) u16 pls[4][32][72];        // per-wave P tile (2 subtiles)
    __shared__ int   bid[2][KTILE];
    __shared__ float bmk[2][KTILE];

    const int bh = blockIdx.y;
    const int b  = bh >> 3;
    const int h  = bh & 7;
    const int q0 = blockIdx.x * QTILE;

    const int tid  = threadIdx.x;
    const int w    = tid >> 6;                // 0..3
    const int lane = tid & 63;
    const int quad = lane >> 4;
    const int l16  = lane & 15;

    const float us2 = u_same[h]  * LOG2E;
    const float uc2 = u_cross[h] * LOG2E;
    const size_t tb = (size_t)bh * (SEQ * HEADDIM);

    // Q A-fragments: subtile s covers rows q0 + s*64 + w*16 .. +15
    bf16x8 aq[2][2];
#pragma unroll
    for (int s = 0; s < 2; ++s) {
        const int qr = q0 + s * 64 + w * 16 + l16;
        aq[s][0] = *(const bf16x8*)(qws + tb + qr * HEADDIM + quad * 8);
        aq[s][1] = *(const bf16x8*)(qws + tb + qr * HEADDIM + 32 + quad * 8);
    }
    int vq[2][4];
#pragma unroll
    for (int s = 0; s < 2; ++s)
#pragma unroll
        for (int r = 0; r < 4; ++r)
            vq[s][r] = vids[b * SEQ + q0 + s * 64 + w * 16 + quad * 4 + r];

    float li[2][4] = {};
    f32x4 o[2][4] = {};

    // stage from LINEAR K (s,d) and V^T (d,s), XOR swizzle on the SOURCE address
    auto stage = [&](int kt, int nb) {
        const int k0 = kt * KTILE;
#pragma unroll
        for (int i = 0; i < 2; ++i) {
            const int srow = w * 16 + i * 8 + (lane >> 3);
            const int scb  = lane & 7;
            const int soff = ((scb ^ (srow & 7)) << 3);
            const int doff = srow * 64 + scb * 8;   // = wave base + lane*8
            gll16(kws + tb + (size_t)(k0 + srow) * HEADDIM + soff, &kbuf[nb][doff]);
            gll16(vtl + tb + (size_t)srow * SEQ + k0 + soff,       &vbuf[nb][doff]);
        }
        if (w == 0) {
            gll4(vids + b * SEQ + k0 + lane, &bid[nb][0]);
            gll4(mask + b * SEQ + k0 + lane, &bmk[nb][0]);
        }
    };

    auto body = [&](const int cur) {   // cur literal at call sites -> const LDS addrs
        // ---- scores -> p = exp2(sc*SCL2 + sel), pack to per-wave LDS ----
#pragma unroll
        for (int nt = 0; nt < 4; ++nt) {
            const int krow = nt * 16 + l16;
            const int r7   = krow & 7;
            const bf16x8 kb0 = *(const bf16x8*)&kbuf[cur][krow * 64 + ((quad ^ r7) << 3)];
            const bf16x8 kb1 = *(const bf16x8*)&kbuf[cur][krow * 64 + ((quad ^ r7 ^ 4) << 3)];
            const int   kv  = bid[cur][krow];
            const float mdl = fmaf(bmk[cur][krow], 1.4426950408889634e9f,
                                   -1.4426950408889634e9f - SHIFT);
            const float as_ = us2 + mdl;
            const float ac_ = uc2 + mdl;
#pragma unroll
            for (int s = 0; s < 2; ++s) {
                f32x4 sc = {};
                sc = MFMA(aq[s][0], kb0, sc);
                sc = MFMA(aq[s][1], kb1, sc);
                float p[4];
#pragma unroll
                for (int r = 0; r < 4; ++r) {
                    const float sel = (kv == vq[s][r]) ? as_ : ac_;
                    p[r] = exp2f(fmaf(sc[r], SCL2, sel));
                    li[s][r] += p[r];
                }
                const unsigned p01 = pk_bf16(p[0], p[1]);
                const unsigned p23 = pk_bf16(p[2], p[3]);
                u16* pb = &pls[w][s * 16 + quad * 4][nt * 16 + l16];
                pb[0]      = (u16)p01;  pb[72]     = (u16)(p01 >> 16);
                pb[2 * 72] = (u16)p23;  pb[3 * 72] = (u16)(p23 >> 16);
            }
        }

        bf16x8 ap[2][2];
#pragma unroll
        for (int s = 0; s < 2; ++s) {
            ap[s][0] = *(const bf16x8*)&pls[w][s * 16 + l16][quad * 8];
            ap[s][1] = *(const bf16x8*)&pls[w][s * 16 + l16][32 + quad * 8];
        }

        // ---- O += P @ V (V frags shared across subtiles) ----
#pragma unroll
        for (int nt = 0; nt < 4; ++nt) {
            const int vrow = nt * 16 + l16;
            const int r7   = vrow & 7;
            const bf16x8 vb0 = *(const bf16x8*)&vbuf[cur][vrow * 64 + ((quad ^ r7) << 3)];
            const bf16x8 vb1 = *(const bf16x8*)&vbuf[cur][vrow * 64 + ((quad ^ r7 ^ 4) << 3)];
#pragma unroll
            for (int s = 0; s < 2; ++s) {
                o[s][nt] = MFMA(ap[s][0], vb0, o[s][nt]);
                o[s][nt] = MFMA(ap[s][1], vb1, o[s][nt]);
            }
        }
    };

    stage(0, 0);
    for (int kt = 0; kt < NKT; kt += 2) {
        __syncthreads();                    // buffer0 staged; everyone done with buffer1
        stage(kt + 1, 1);
        body(0);
        __syncthreads();                    // buffer1 staged; everyone done with buffer0
        if (kt + 2 < NKT) stage(kt + 2, 0);
        body(1);
    }

    // ---- epilogue: reduce li across the quad-row group, normalize, write ----
#pragma unroll
    for (int s = 0; s < 2; ++s)
#pragma unroll
        for (int r = 0; r < 4; ++r) {
            const float inv = 1.0f / qsum16(li[s][r]);
            const int R = q0 + s * 64 + w * 16 + quad * 4 + r;
            const int rb = (b * SEQ + R) * DMODEL + h * HEADDIM;
#pragma unroll
            for (int nt = 0; nt < 4; ++nt)
                attn[rb + nt * 16 + l16] = f2bf(o[s][nt][r] * inv);
        }
}

// ---------------- kernel 3: output projection (128x128, LDS-staged, fp32 out) ----------------
__global__ __launch_bounds__(256) void proj_kernel(
    const u16* __restrict__ a, const u16* __restrict__ Wo,
    const float* __restrict__ bo, float* __restrict__ out)
{
    __shared__ alignas(16) u16 As[128 * 64];
    __shared__ alignas(16) u16 Bs[128 * 64];

    const int m0 = blockIdx.x * 128;
    const int n0 = blockIdx.y * 128;         // [0,512)
    const int tid  = threadIdx.x;
    const int w    = tid >> 6;
    const int lane = tid & 63;
    const int quad = lane >> 4;
    const int l16  = lane & 15;
    const int wm = w & 1, wn = w >> 1;

    f32x4 acc[4][4] = {};

    for (int kb = 0; kb < 8; ++kb) {
#pragma unroll
        for (int it = 0; it < 4; ++it) {
            const int s   = it * 256 + tid;
            const int row = s >> 3;
            const int cb  = s & 7;
            const int gcol = kb * 64 + (((cb ^ (row & 7))) << 3);
            gll16(a  + (m0 + row) * 512 + gcol, &As[s * 8]);
            gll16(Wo + (n0 + row) * 512 + gcol, &Bs[s * 8]);
        }
        __syncthreads();

#pragma unroll
        for (int ks = 0; ks < 2; ++ks) {
            bf16x8 av[4], bv[4];
#pragma unroll
            for (int t = 0; t < 4; ++t) {
                const int arow = wm * 64 + t * 16 + l16;
                av[t] = *(const bf16x8*)&As[arow * 64 + (((ks * 4 + quad) ^ (arow & 7)) << 3)];
                const int brow = wn * 64 + t * 16 + l16;
                bv[t] = *(const bf16x8*)&Bs[brow * 64 + (((ks * 4 + quad) ^ (brow & 7)) << 3)];
            }
#pragma unroll
            for (int tm = 0; tm < 4; ++tm)
#pragma unroll
                for (int tn = 0; tn < 4; ++tn)
                    acc[tm][tn] = MFMA(av[tm], bv[tn], acc[tm][tn]);
        }
        __syncthreads();
    }

#pragma unroll
    for (int tm = 0; tm < 4; ++tm) {
#pragma unroll
        for (int tn = 0; tn < 4; ++tn) {
            const int col = n0 + wn * 64 + tn * 16 + l16;
            const float bval = bo[col];
#pragma unroll
            for (int r = 0; r < 4; ++r) {
                const int R = m0 + wm * 64 + tm * 16 + quad * 4 + r;
                out[R * 512 + col] = acc[tm][tn][r] + bval;
            }
        }
    }
}

// ---------------- launch ----------------
extern "C" void kernel_launch(void* const* d_in, const int* in_sizes, int n_in,
                              void* d_out, int out_size, void* d_ws, size_t ws_size,
                              hipStream_t stream) {
    const float* x    = (const float*)d_in[0];
    const int*   vids = (const int*)d_in[1];
    const float* mask = (const float*)d_in[2];
    const float* Wq = (const float*)d_in[3];
    const float* bq = (const float*)d_in[4];
    const float* Wk = (const float*)d_in[5];
    const float* bk = (const float*)d_in[6];
    const float* Wv = (const float*)d_in[7];
    const float* bv = (const float*)d_in[8];
    const float* Wo = (const float*)d_in[9];
    const float* bo = (const float*)d_in[10];
    const float* usame  = (const float*)d_in[11];
    const float* ucross = (const float*)d_in[12];
    float* out = (float*)d_out;

    // workspace layout (~35 MB total)
    u16* xbf  = (u16*)d_ws;                 // 8 MB; reused as attention output
    u16* wqbf = xbf + NX;                   // 512 KB each
    u16* wkbf = wqbf + NW;
    u16* wvbf = wkbf + NW;
    u16* wobf = wvbf + NW;
    float2* cst = (float2*)(wobf + NW);     // 512 KB (2048 x 32 float2)
    u16* qws  = (u16*)(cst + SEQ * 32);     // 8 MB each
    u16* kws  = qws + (size_t)BATCH * NHEADS * SEQ * HEADDIM;
    u16* vtws = kws + (size_t)BATCH * NHEADS * SEQ * HEADDIM;
    u16* attn = xbf;   // reuse: qkv_kernel has finished with xbf before attn writes

    cvt_rope_kernel<<<(NCVT4 + SEQ * 32 / 4 + 255) / 256, 256, 0, stream>>>(
        x, Wq, Wk, Wv, Wo, xbf, wqbf, wkbf, wvbf, wobf, cst);

    dim3 g1(MTOT / 128, 3 * DMODEL / 128);  // 64 x 12
    qkv_kernel<<<g1, 256, 0, stream>>>(xbf, wqbf, bq, wkbf, bk, wvbf, bv,
                                       cst, qws, kws, vtws);

    dim3 g2(SEQ / QTILE, BATCH * NHEADS);   // 16 x 32
    attn_kernel<<<g2, 256, 0, stream>>>(qws, kws, vtws, vids, mask,
                                        usame, ucross, attn);

    dim3 g3(MTOT / 128, DMODEL / 128);      // 64 x 4
    proj_kernel<<<g3, 256, 0, stream>>>(attn, wobf, bo, out);
}

// Round 9
// 204.815 us; speedup vs baseline: 1.0505x; 1.0505x over previous
//
#include <hip/hip_runtime.h>
#include <hip/hip_bf16.h>

// ---------------- problem constants ----------------
#define BATCH   4
#define SEQ     2048
#define DMODEL  512
#define NHEADS  8
#define HEADDIM 64
#define MTOT    (BATCH*SEQ)      // 8192 rows
#define NX      (MTOT*DMODEL)    // 4194304 x elements
#define NW      (DMODEL*DMODEL)  // 262144 weight elements
#define QTILE   128
#define KTILE   64
#define NKT     (SEQ/KTILE)      // 32

#define LOG2E   1.4426950408889634f
#define SCL2    0.18033688011112042f      // 0.125 * log2e
#define SHIFT   14.426950408889634f       // overflow headroom shift
// ---------------------------------------------------

typedef unsigned short u16;
typedef __bf16 bf16x8 __attribute__((ext_vector_type(8)));
typedef float  f32x4  __attribute__((ext_vector_type(4)));
typedef unsigned short u16x4 __attribute__((ext_vector_type(4)));
typedef unsigned u32x2 __attribute__((ext_vector_type(2)));

#define MFMA(a,b,c) __builtin_amdgcn_mfma_f32_16x16x32_bf16(a,b,c,0,0,0)

__device__ __forceinline__ u16 f2bf(float f) {
    unsigned u = __float_as_uint(f);
    u += 0x7FFFu + ((u >> 16) & 1u);   // RNE
    return (u16)(u >> 16);
}
__device__ __forceinline__ unsigned pk_bf16(float a, float b) {
    union { __hip_bfloat162 h; unsigned u; } cv;
    cv.h = __float22bfloat162_rn(make_float2(a, b));
    return cv.u;
}
__device__ __forceinline__ float qsum16(float v) {
    v += __shfl_xor(v, 1);
    v += __shfl_xor(v, 2);
    v += __shfl_xor(v, 4);
    v += __shfl_xor(v, 8);
    return v;
}
__device__ __forceinline__ void gll16(const void* g, void* l) {
    __builtin_amdgcn_global_load_lds((const __attribute__((address_space(1))) void*)g,
                                     (__attribute__((address_space(3))) void*)l, 16, 0, 0);
}
__device__ __forceinline__ void gll4(const void* g, void* l) {
    __builtin_amdgcn_global_load_lds((const __attribute__((address_space(1))) void*)g,
                                     (__attribute__((address_space(3))) void*)l, 4, 0, 0);
}

// ---------------- kernel 0: fp32 -> bf16 converts + rope cos/sin table ----------------
#define NCVT4 ((NX + 4*NW)/4)    // 1310720 float4 groups
__global__ __launch_bounds__(256) void cvt_rope_kernel(
    const float* __restrict__ x,
    const float* __restrict__ wq, const float* __restrict__ wk,
    const float* __restrict__ wv, const float* __restrict__ wo,
    u16* __restrict__ xbf,
    u16* __restrict__ wqbf, u16* __restrict__ wkbf,
    u16* __restrict__ wvbf, u16* __restrict__ wobf,
    float2* __restrict__ cst)
{
    int i4 = blockIdx.x * 256 + threadIdx.x;
    if (i4 < NCVT4) {
        int i = i4 * 4;
        const float* s; u16* d; int o;
        if (i < NX) { s = x; d = xbf; o = i; }
        else {
            int j = i - NX;
            int r = j >> 18;            // NW = 2^18
            o = j & (NW - 1);
            s = (r == 0) ? wq : (r == 1) ? wk : (r == 2) ? wv : wo;
            d = (r == 0) ? wqbf : (r == 1) ? wkbf : (r == 2) ? wvbf : wobf;
        }
        float4 v = *(const float4*)(s + o);
        u16x4 u = { f2bf(v.x), f2bf(v.y), f2bf(v.z), f2bf(v.w) };
        *(u16x4*)(d + o) = u;
    } else {
        int r = i4 - NCVT4;             // [0, 16384)
        if (r < SEQ * 32 / 4) {
            int idx = r * 4;
            int s  = idx >> 5;
            int p0 = idx & 31;
#pragma unroll
            for (int t = 0; t < 4; ++t) {
                int p = p0 + t;
                float inv = __expf(-0.5756462732485115f * (float)(p & 15));
                float ang = (float)s * inv;
                cst[idx + t] = make_float2(cosf(ang), sinf(ang));
            }
        }
    }
}

// ---------------- kernel 1: fused QKV projection + RoPE (128x128, LDS-staged) ----------------
// Q/K blocks: MFMA(A=W, B=x) -> C rows = head-dims (rope in-register), LDS bounce,
//             coalesced b128 stores, linear (bh, s, d).
// V blocks:   MFMA(A=x, B=W) -> LDS transpose, V^T (bh, d, s) coalesced stores.
// Fragment row bases are selected PER SECTION so the C-layout matches each epilogue:
//   Q/K: x rows on wn (C col), W rows on wm (C row).
//   V  : x rows on wm (C row), W rows on wn (C col).
#define TP 136   // LDS tile row stride (u16 elems)
__global__ __launch_bounds__(256) void qkv_kernel(
    const u16* __restrict__ x,
    const u16* __restrict__ Wq, const float* __restrict__ bq,
    const u16* __restrict__ Wk, const float* __restrict__ bk,
    const u16* __restrict__ Wv, const float* __restrict__ bv,
    const float* __restrict__ cstf,     // cst as float*, {cos,sin} interleaved
    u16* __restrict__ qws, u16* __restrict__ kws, u16* __restrict__ vtws)
{
    __shared__ alignas(16) u16 smem[128 * TP];   // 34816 B; As/Bs alias the front
    u16* As = smem;            // x tile   128x64
    u16* Bs = smem + 8192;     // W tile   128x64

    const int m0 = blockIdx.x * 128;         // x-row tile
    const int n0 = blockIdx.y * 128;         // col tile over 1536
    const int tid  = threadIdx.x;
    const int w    = tid >> 6;
    const int lane = tid & 63;
    const int quad = lane >> 4;
    const int l16  = lane & 15;
    const int wm = w & 1, wn = w >> 1;

    const int sec = n0 >> 9;                 // 0=Q 1=K 2=V
    const int oc0 = n0 & 511;
    const u16*   Wm = (sec == 0) ? Wq : (sec == 1 ? Wk : Wv);
    const float* bb = (sec == 0) ? bq : (sec == 1 ? bk : bv);

    const int xb = (sec < 2) ? wn : wm;      // x-row fragment base
    const int wb = (sec < 2) ? wm : wn;      // W-row fragment base

    f32x4 acc[4][4] = {};

    for (int kb = 0; kb < 8; ++kb) {
#pragma unroll
        for (int it = 0; it < 4; ++it) {
            const int s   = it * 256 + tid;
            const int row = s >> 3;
            const int cb  = s & 7;
            const int gcol = kb * 64 + (((cb ^ (row & 7))) << 3);
            gll16(x  + (m0  + row) * 512 + gcol, &As[s * 8]);
            gll16(Wm + (oc0 + row) * 512 + gcol, &Bs[s * 8]);
        }
        __syncthreads();

#pragma unroll
        for (int ks = 0; ks < 2; ++ks) {
            bf16x8 xf[4], wf[4];
#pragma unroll
            for (int t = 0; t < 4; ++t) {
                const int xrow = xb * 64 + t * 16 + l16;
                const int wrow = wb * 64 + t * 16 + l16;
                xf[t] = *(const bf16x8*)&As[xrow * 64 + (((ks * 4 + quad) ^ (xrow & 7)) << 3)];
                wf[t] = *(const bf16x8*)&Bs[wrow * 64 + (((ks * 4 + quad) ^ (wrow & 7)) << 3)];
            }
            if (sec < 2) {
#pragma unroll
                for (int tm = 0; tm < 4; ++tm)
#pragma unroll
                    for (int tn = 0; tn < 4; ++tn)
                        acc[tm][tn] = MFMA(wf[tm], xf[tn], acc[tm][tn]);  // C row=d, col=s
            } else {
#pragma unroll
                for (int tm = 0; tm < 4; ++tm)
#pragma unroll
                    for (int tn = 0; tn < 4; ++tn)
                        acc[tm][tn] = MFMA(xf[tm], wf[tn], acc[tm][tn]);  // C row=s, col=d
            }
        }
        __syncthreads();
    }

    if (sec < 2) {
        // ---- Q/K epilogue: C row = head-dim, col = s. rope fully in-register ----
#pragma unroll
        for (int tm = 0; tm < 4; ++tm) {
            const int dls = wm * 64 + tm * 16 + quad * 4;         // local d base (mult of 4)
            const float4 bv4 = *(const float4*)&bb[oc0 + dls];
            const int pbase = ((oc0 + dls) & 63) >> 1;            // rope pair idx (even)
#pragma unroll
            for (int tn = 0; tn < 4; ++tn) {
                const int sl = wn * 64 + tn * 16 + l16;           // local s
                const int sg = (m0 + sl) & 2047;                  // seq pos
                const float4 cs = *(const float4*)&cstf[sg * 64 + pbase * 2]; // c0,s0,c1,s1
                const float v0 = acc[tm][tn][0] + bv4.x;
                const float v1 = acc[tm][tn][1] + bv4.y;
                const float v2 = acc[tm][tn][2] + bv4.z;
                const float v3 = acc[tm][tn][3] + bv4.w;
                const float r0 = v0 * cs.x - v1 * cs.y;
                const float r1 = v1 * cs.x + v0 * cs.y;
                const float r2 = v2 * cs.z - v3 * cs.w;
                const float r3 = v3 * cs.z + v2 * cs.w;
                u32x2 pv = { pk_bf16(r0, r1), pk_bf16(r2, r3) };
                *(u32x2*)&smem[sl * TP + dls] = pv;
            }
        }
        __syncthreads();
        u16* dst0 = (sec == 0) ? qws : kws;
#pragma unroll
        for (int i = 0; i < 8; ++i) {
            const int c   = i * 256 + tid;       // [0, 2048)
            const int sl  = c >> 4;              // local s row
            const int d8  = (c & 15) * 8;        // 8-dim chunk
            const int gcol = oc0 + d8;
            const int hh  = gcol >> 6;
            const int dh  = gcol & 63;
            const int sgl = m0 + sl;
            const int bi  = sgl >> 11;
            const int s   = sgl & 2047;
            u16* dst = dst0 + (size_t)(bi * NHEADS + hh) * (SEQ * HEADDIM)
                            + (size_t)s * HEADDIM + dh;
            *(bf16x8*)dst = *(const bf16x8*)&smem[sl * TP + d8];
        }
    } else {
        // ---- V epilogue: C row = s, col = out-col d. LDS transpose T[d][s] ----
#pragma unroll
        for (int tm = 0; tm < 4; ++tm) {
            const int row_l = wm * 64 + tm * 16 + quad * 4;      // local s rows
#pragma unroll
            for (int tn = 0; tn < 4; ++tn) {
                const int col_l = wn * 64 + tn * 16 + l16;       // local out-col
                const float bval = bb[oc0 + col_l];
                u32x2 pv = { pk_bf16(acc[tm][tn][0] + bval, acc[tm][tn][1] + bval),
                             pk_bf16(acc[tm][tn][2] + bval, acc[tm][tn][3] + bval) };
                *(u32x2*)&smem[col_l * TP + row_l] = pv;
            }
        }
        __syncthreads();
        const int bi  = m0 >> 11;
        const int sgb = m0 & 2047;
#pragma unroll
        for (int i = 0; i < 8; ++i) {
            const int c    = i * 256 + tid;      // [0, 2048)
            const int col  = c >> 4;             // local out-col
            const int sc8  = (c & 15) * 8;       // s-chunk
            const int gcol = oc0 + col;
            const int hh   = gcol >> 6;
            const int d    = gcol & 63;
            u16* dst = vtws + (size_t)(bi * NHEADS + hh) * (SEQ * HEADDIM)
                            + (size_t)d * SEQ + sgb + sc8;
            *(bf16x8*)dst = *(const bf16x8*)&smem[col * TP + sc8];
        }
    }
}

// ---------------- kernel 2: flash attention (round-6 structure) ----------------
// grid: (SEQ/QTILE, B*H) = (16, 32). block 512 = 8 waves; each wave owns 16 q rows.
__global__ __launch_bounds__(512, 4) void attn_kernel(
    const u16* __restrict__ qws, const u16* __restrict__ kws,
    const u16* __restrict__ vtl,
    const int* __restrict__ vids, const float* __restrict__ mask,
    const float* __restrict__ u_same, const float* __restrict__ u_cross,
    u16* __restrict__ attn)
{
    __shared__ alignas(16) u16 kbuf[2][KTILE * 64];   // 8 KB each, swizzled tiles
    __shared__ alignas(16) u16 vbuf[2][KTILE * 64];
    __shared__ alignas(16) u16 pls[8][16][72];        // per-wave P tile, padded
    __shared__ int   bid[2][KTILE];
    __shared__ float bmk[2][KTILE];

    const int bh = blockIdx.y;
    const int b  = bh >> 3;
    const int h  = bh & 7;
    const int q0 = blockIdx.x * QTILE;

    const int tid  = threadIdx.x;
    const int w    = tid >> 6;                // 0..7
    const int lane = tid & 63;
    const int quad = lane >> 4;
    const int l16  = lane & 15;

    const float us2 = u_same[h]  * LOG2E;
    const float uc2 = u_cross[h] * LOG2E;
    const size_t tb = (size_t)bh * (SEQ * HEADDIM);

    const int qr = q0 + w * 16 + l16;
    const bf16x8 aq0 = *(const bf16x8*)(qws + tb + qr * HEADDIM + quad * 8);
    const bf16x8 aq1 = *(const bf16x8*)(qws + tb + qr * HEADDIM + 32 + quad * 8);

    int vq[4];
#pragma unroll
    for (int r = 0; r < 4; ++r)
        vq[r] = vids[b * SEQ + q0 + w * 16 + quad * 4 + r];

    float li[4] = {0.f, 0.f, 0.f, 0.f};
    f32x4 o[4] = {};

    // stage from LINEAR K (s,d) and V^T (d,s), XOR swizzle on the SOURCE address
    const int srow = w * 8 + (lane >> 3);     // tile row this lane stages
    const int scb  = lane & 7;
    const int soff = ((scb ^ (srow & 7)) << 3);
    auto stage = [&](int kt, int nb) {
        const int k0 = kt * KTILE;
        gll16(kws + tb + (size_t)(k0 + srow) * HEADDIM + soff, &kbuf[nb][w * 512 + lane * 8]);
        gll16(vtl + tb + (size_t)srow * SEQ + k0 + soff,       &vbuf[nb][w * 512 + lane * 8]);
        if (w == 0) {
            gll4(vids + b * SEQ + k0 + lane, &bid[nb][0]);
            gll4(mask + b * SEQ + k0 + lane, &bmk[nb][0]);
        }
    };

    auto body = [&](const int cur) {   // cur literal at call sites -> const LDS addrs
#pragma unroll
        for (int nt = 0; nt < 4; ++nt) {
            const int krow = nt * 16 + l16;
            const int r7   = krow & 7;
            const bf16x8 kb0 = *(const bf16x8*)&kbuf[cur][krow * 64 + ((quad ^ r7) << 3)];
            const bf16x8 kb1 = *(const bf16x8*)&kbuf[cur][krow * 64 + ((quad ^ r7 ^ 4) << 3)];
            f32x4 sc = {};
            sc = MFMA(aq0, kb0, sc);
            sc = MFMA(aq1, kb1, sc);
            const int   kv  = bid[cur][krow];
            const float mdl = fmaf(bmk[cur][krow], 1.4426950408889634e9f,
                                   -1.4426950408889634e9f - SHIFT);
            const float as_ = us2 + mdl;
            const float ac_ = uc2 + mdl;
            float p[4];
#pragma unroll
            for (int r = 0; r < 4; ++r) {
                const float sel = (kv == vq[r]) ? as_ : ac_;
                p[r] = exp2f(fmaf(sc[r], SCL2, sel));
                li[r] += p[r];
            }
            const unsigned p01 = pk_bf16(p[0], p[1]);
            const unsigned p23 = pk_bf16(p[2], p[3]);
            u16* pb = &pls[w][quad * 4][nt * 16 + l16];
            pb[0]       = (u16)p01;  pb[72]      = (u16)(p01 >> 16);
            pb[2 * 72]  = (u16)p23;  pb[3 * 72]  = (u16)(p23 >> 16);
        }

        const bf16x8 ap0 = *(const bf16x8*)&pls[w][l16][quad * 8];
        const bf16x8 ap1 = *(const bf16x8*)&pls[w][l16][32 + quad * 8];

#pragma unroll
        for (int nt = 0; nt < 4; ++nt) {
            const int vrow = nt * 16 + l16;
            const int r7   = vrow & 7;
            const bf16x8 vb0 = *(const bf16x8*)&vbuf[cur][vrow * 64 + ((quad ^ r7) << 3)];
            const bf16x8 vb1 = *(const bf16x8*)&vbuf[cur][vrow * 64 + ((quad ^ r7 ^ 4) << 3)];
            o[nt] = MFMA(ap0, vb0, o[nt]);
            o[nt] = MFMA(ap1, vb1, o[nt]);
        }
    };

    stage(0, 0);
    for (int kt = 0; kt < NKT; kt += 2) {
        __syncthreads();
        stage(kt + 1, 1);
        body(0);
        __syncthreads();
        if (kt + 2 < NKT) stage(kt + 2, 0);
        body(1);
    }

#pragma unroll
    for (int r = 0; r < 4; ++r) {
        const float inv = 1.0f / qsum16(li[r]);
        const int R = q0 + w * 16 + quad * 4 + r;
        const int rb = (b * SEQ + R) * DMODEL + h * HEADDIM;
#pragma unroll
        for (int nt = 0; nt < 4; ++nt)
            attn[rb + nt * 16 + l16] = f2bf(o[nt][r] * inv);
    }
}

// ---------------- kernel 3: output projection (swapped A/B, LDS store, fp32 out) ----------------
__global__ __launch_bounds__(256) void proj_kernel(
    const u16* __restrict__ a, const u16* __restrict__ Wo,
    const float* __restrict__ bo, float* __restrict__ out)
{
    __shared__ alignas(16) u16 psm[132 * 64 * 2];    // 33792 B; As/Bs alias front, Lp aliases all
    u16* As = psm;
    u16* Bs = psm + 8192;
    float* Lp = (float*)psm;                         // 64 x 132 f32 tile

    const int m0 = blockIdx.x * 128;                 // attn-row tile
    const int n0 = blockIdx.y * 128;                 // out-col strip
    const int tid  = threadIdx.x;
    const int w    = tid >> 6;
    const int lane = tid & 63;
    const int quad = lane >> 4;
    const int l16  = lane & 15;
    const int wm = w & 1, wn = w >> 1;               // wm: W-col tile, wn: s tile

    f32x4 acc[4][4] = {};

    for (int kb = 0; kb < 8; ++kb) {
#pragma unroll
        for (int it = 0; it < 4; ++it) {
            const int s   = it * 256 + tid;
            const int row = s >> 3;
            const int cb  = s & 7;
            const int gcol = kb * 64 + (((cb ^ (row & 7))) << 3);
            gll16(a  + (m0 + row) * 512 + gcol, &As[s * 8]);
            gll16(Wo + (n0 + row) * 512 + gcol, &Bs[s * 8]);
        }
        __syncthreads();

#pragma unroll
        for (int ks = 0; ks < 2; ++ks) {
            bf16x8 af[4], wf[4];
#pragma unroll
            for (int t = 0; t < 4; ++t) {
                const int arow = wn * 64 + t * 16 + l16;
                const int wrow = wm * 64 + t * 16 + l16;
                af[t] = *(const bf16x8*)&As[arow * 64 + (((ks * 4 + quad) ^ (arow & 7)) << 3)];
                wf[t] = *(const bf16x8*)&Bs[wrow * 64 + (((ks * 4 + quad) ^ (wrow & 7)) << 3)];
            }
#pragma unroll
            for (int tm = 0; tm < 4; ++tm)
#pragma unroll
                for (int tn = 0; tn < 4; ++tn)
                    acc[tm][tn] = MFMA(wf[tm], af[tn], acc[tm][tn]);  // C row=d, col=s
        }
        __syncthreads();
    }

    // two phases by s-half: waves wn==hph write Lp[s2][d], all threads store coalesced
#pragma unroll
    for (int hph = 0; hph < 2; ++hph) {
        if (wn == hph) {
#pragma unroll
            for (int tm = 0; tm < 4; ++tm) {
                const int dls = wm * 64 + tm * 16 + quad * 4;
                const float4 bv4 = *(const float4*)&bo[n0 + dls];
#pragma unroll
                for (int tn = 0; tn < 4; ++tn) {
                    const int s2 = tn * 16 + l16;            // [0,64)
                    float4 v = { acc[tm][tn][0] + bv4.x, acc[tm][tn][1] + bv4.y,
                                 acc[tm][tn][2] + bv4.z, acc[tm][tn][3] + bv4.w };
                    *(float4*)&Lp[s2 * 132 + dls] = v;
                }
            }
        }
        __syncthreads();
#pragma unroll
        for (int i = 0; i < 8; ++i) {
            const int c  = i * 256 + tid;        // [0,2048)
            const int s2 = c >> 5;               // [0,64)
            const int dq = (c & 31) * 4;         // [0,128)
            float4 v = *(const float4*)&Lp[s2 * 132 + dq];
            *(float4*)&out[(size_t)(m0 + hph * 64 + s2) * 512 + n0 + dq] = v;
        }
        __syncthreads();
    }
}

// ---------------- launch ----------------
extern "C" void kernel_launch(void* const* d_in, const int* in_sizes, int n_in,
                              void* d_out, int out_size, void* d_ws, size_t ws_size,
                              hipStream_t stream) {
    const float* x    = (const float*)d_in[0];
    const int*   vids = (const int*)d_in[1];
    const float* mask = (const float*)d_in[2];
    const float* Wq = (const float*)d_in[3];
    const float* bq = (const float*)d_in[4];
    const float* Wk = (const float*)d_in[5];
    const float* bk = (const float*)d_in[6];
    const float* Wv = (const float*)d_in[7];
    const float* bv = (const float*)d_in[8];
    const float* Wo = (const float*)d_in[9];
    const float* bo = (const float*)d_in[10];
    const float* usame  = (const float*)d_in[11];
    const float* ucross = (const float*)d_in[12];
    float* out = (float*)d_out;

    u16* xbf  = (u16*)d_ws;                 // 8 MB; reused as attention output
    u16* wqbf = xbf + NX;                   // 512 KB each
    u16* wkbf = wqbf + NW;
    u16* wvbf = wkbf + NW;
    u16* wobf = wvbf + NW;
    float2* cst = (float2*)(wobf + NW);     // 512 KB
    u16* qws  = (u16*)(cst + SEQ * 32);     // 8 MB each
    u16* kws  = qws + (size_t)BATCH * NHEADS * SEQ * HEADDIM;
    u16* vtws = kws + (size_t)BATCH * NHEADS * SEQ * HEADDIM;
    u16* attn = xbf;

    cvt_rope_kernel<<<(NCVT4 + SEQ * 32 / 4 + 255) / 256, 256, 0, stream>>>(
        x, Wq, Wk, Wv, Wo, xbf, wqbf, wkbf, wvbf, wobf, cst);

    dim3 g1(MTOT / 128, 3 * DMODEL / 128);  // 64 x 12
    qkv_kernel<<<g1, 256, 0, stream>>>(xbf, wqbf, bq, wkbf, bk, wvbf, bv,
                                       (const float*)cst, qws, kws, vtws);

    dim3 g2(SEQ / QTILE, BATCH * NHEADS);   // 16 x 32
    attn_kernel<<<g2, 512, 0, stream>>>(qws, kws, vtws, vids, mask,
                                        usame, ucross, attn);

    dim3 g3(MTOT / 128, DMODEL / 128);      // 64 x 4
    proj_kernel<<<g3, 256, 0, stream>>>(attn, wobf, bo, out);
}